// Round 5
// baseline (706.148 us; speedup 1.0000x reference)
//
#include <hip/hip_runtime.h>
#include <hip/hip_bf16.h>
#include <cstdint>
#include <cstddef>

#define B_ 128
#define S_ 256
#define TOK (B_*S_)   // 32768

typedef _Float16 f16;
typedef _Float16 f16x2 __attribute__((ext_vector_type(2)));

__device__ __forceinline__ float sigf(float x) {
    return __builtin_amdgcn_rcpf(1.0f + __expf(-x));
}
__device__ __forceinline__ float tanhfast(float x) {
    return 1.0f - 2.0f * __builtin_amdgcn_rcpf(1.0f + __expf(2.0f * x));
}
__device__ __forceinline__ float bf2f(unsigned short v) {
    union { unsigned u; float f; } c; c.u = ((unsigned)v) << 16; return c.f;
}
// packed f16 dot2 with f32 accumulate: d = a.x*b.x + a.y*b.y + c (VOP3P)
__device__ __forceinline__ float dot2(f16x2 a, f16x2 b, float c) {
    float d;
    asm("v_dot2_f32_f16 %0, %1, %2, %3" : "=v"(d) : "v"(a), "v"(b), "v"(c));
    return d;
}
__device__ __forceinline__ f16x2 u2h2(uint32_t v) {
    union { uint32_t u; f16x2 h; } c; c.u = v; return c.h;
}

// ---- K1: char input-gate table: gin[dir][c][row] = b[row] + Wih[row,:]·emb[c,:]
__global__ void k_gin(const float* __restrict__ ce,
                      const float* __restrict__ wih_f, const float* __restrict__ b_f,
                      const float* __restrict__ wih_b, const float* __restrict__ b_b,
                      float* __restrict__ gin) {
    int tid = blockIdx.x * blockDim.x + threadIdx.x;
    if (tid >= 200) return;
    int dir = tid / 100, row = tid % 100;
    const float* wih = dir ? wih_b : wih_f;
    float bias = dir ? b_b[row] : b_f[row];
    for (int c = 0; c < 100; ++c) {
        float s = bias;
#pragma unroll
        for (int k = 0; k < 25; ++k) s += wih[row*25 + k] * ce[c*25 + k];
        gin[(dir*100 + c)*100 + row] = s;
    }
}

// ---- K1b: combined word-input weight [800][152] (k-padded) + bias [800]
__global__ void k_wcomb(const float* __restrict__ wih_f, const float* __restrict__ bf,
                        const float* __restrict__ wih_b, const float* __restrict__ bb,
                        float* __restrict__ Wc, float* __restrict__ bc) {
    int idx = blockIdx.x * blockDim.x + threadIdx.x;
    if (idx < 800*152) {
        int n = idx / 152, k = idx - n*152;
        int dir = n >= 400 ? 1 : 0, r = n - dir*400;
        const float* w = dir ? wih_b : wih_f;
        Wc[idx] = (k < 150) ? w[r*150 + k] : 0.0f;
    }
    if (idx < 800) {
        int dir = idx >= 400 ? 1 : 0, r = idx - dir*400;
        bc[idx] = dir ? bb[r] : bf[r];
    }
}

// ---- K1c: char Whh -> f16 table [dir*4+gate][unit=25][j-padded 26]
__global__ void k_wpad(const float* __restrict__ whh_f, const float* __restrict__ whh_b,
                       unsigned short* __restrict__ wpadh) {
    int idx = blockIdx.x * blockDim.x + threadIdx.x;
    if (idx >= 2*4*25*26) return;
    int j  = idx % 26;
    int r  = idx / 26;        // r = (dir*4+gate)*25 + u
    int u  = r % 25;
    int gk = r / 25;          // dir*4+gate
    int gate = gk & 3;
    const float* w = (gk >= 4) ? whh_b : whh_f;
    float v = (j < 25) ? w[(gate*25 + u)*25 + j] : 0.f;
    union { f16 h; unsigned short s; } c; c.h = (f16)v;
    wpadh[idx] = c.s;
}

// ---- K2: char BiLSTM. 8 groups of 32 lanes per block; h exchanged via LDS (f16).
//      v_dot2_f32_f16 weights (52 dwords/thread), rolled loop, gin prefetch.
__global__ __launch_bounds__(256)
__attribute__((amdgpu_waves_per_eu(2, 2)))
void k_char(
        const unsigned short* __restrict__ wpadh, const float* __restrict__ gin,
        const int* __restrict__ char_ids, const int* __restrict__ word_num,
        float* __restrict__ wfbuf) {
    __shared__ uint32_t hsm[8][16];              // f16x2 h, 13 dwords used + pad
    __shared__ int chl[4][16];                   // per-word char ids
    int tid  = threadIdx.x;
    int grp  = tid >> 5, lane = tid & 31;
    int g    = blockIdx.x * 8 + grp;        // (word,dir) id: 0..65535
    int word = g >> 1, dir = g & 1;
    int b    = word >> 8, s = word & 255;
    int wd   = grp >> 1;                    // word slot in block: 0..3
    if (tid < 64) {
        int w = blockIdx.x * 4 + (tid >> 4);
        chl[tid >> 4][tid & 15] = char_ids[w*16 + (tid & 15)];
    }
    int u = (lane < 25) ? lane : 0;
    // weights: w[gate][i] = f16x2 pair (j=2i, 2i+1); row stride 13 dwords
    f16x2 w[4][13];
    const uint32_t* wp32 = (const uint32_t*)wpadh;
#pragma unroll
    for (int gi = 0; gi < 4; ++gi)
#pragma unroll
        for (int i = 0; i < 13; ++i)
            w[gi][i] = u2h2(wp32[(((size_t)dir*4 + gi)*25 + u)*13 + i]);
    if (lane < 16) hsm[grp][lane] = 0;      // h0 = 0 incl. pad
    __syncthreads();                        // chl visible to all groups
    float h = 0.f, c = 0.f;
    const float* ginD = gin + dir*100*100;
    int t0 = dir ? 15 : 0;
    const float* gv = ginD + chl[wd][t0]*100;
    float ai = gv[u], af = gv[25 + u], ag = gv[50 + u], ao = gv[75 + u];
#pragma unroll 1
    for (int tt = 0; tt < 16; ++tt) {
        float bi = ai, bff = af, bg = ag, bo = ao;
        if (tt < 15) {
            int tn = dir ? (14 - tt) : (tt + 1);
            const float* gn = ginD + chl[wd][tn]*100;
            ai = gn[u]; af = gn[25 + u]; ag = gn[50 + u]; ao = gn[75 + u];
        }
        const uint32_t* hp = hsm[grp];
#pragma unroll
        for (int i = 0; i < 13; ++i) {
            f16x2 h2 = u2h2(hp[i]);   // same-addr broadcast within group (free)
            bi  = dot2(w[0][i], h2, bi);
            bff = dot2(w[1][i], h2, bff);
            bg  = dot2(w[2][i], h2, bg);
            bo  = dot2(w[3][i], h2, bo);
        }
        c = sigf(bff)*c + sigf(bi)*tanhfast(bg);
        h = sigf(bo)*tanhfast(c);
        if (lane < 25) {
            union { f16 hh; unsigned short us; } cv; cv.hh = (f16)h;
            ((unsigned short*)hsm[grp])[u] = cv.us;   // wave-synchronous DS pipe
        }
    }
    if (lane < 25) {
        float m = (s < word_num[b]) ? 1.f : 0.f;
        wfbuf[(size_t)word*152 + 100 + dir*25 + lane] = h * m;  // [hf | hb], masked
    }
}

// ---- K3a: gather word embeddings into wfbuf[:,0:100]; zero k-pad 150..151
__global__ void k_gather(const float* __restrict__ we, const int* __restrict__ wids,
                         float* __restrict__ wfbuf) {
    int idx = blockIdx.x * blockDim.x + threadIdx.x;
    if (idx >= TOK*152) return;
    int t = idx / 152, e = idx - t*152;
    if (e < 100)        wfbuf[idx] = we[(size_t)wids[t]*100 + e];
    else if (e >= 150)  wfbuf[idx] = 0.f;
}

// ---- K3b: word input gates GEMM  [32768,152] @ [152,800] -> bf16 gates.
//      v4: gate layout packed per unit: gates[(dir*TOK+tok)*400 + u*4 + gate]
//      so k_word reads one aligned 8B quad per (thread,step).
__global__ __launch_bounds__(256) void k_gemm_in(
        const float* __restrict__ A, const float* __restrict__ Wc,
        const float* __restrict__ bc, __hip_bfloat16* __restrict__ gates) {
    __shared__ float As[8][64];
    __shared__ float Bs[8][64];
    int tid = threadIdx.x;
    int tileM = blockIdx.x & 511;
    int tileN = blockIdx.x >> 9;        // 0..12
    int m0 = tileM*64, n0 = tileN*64;
    int ty = tid >> 4, tx = tid & 15;
    int a_m = tid >> 2, a_k = (tid & 3)*2;
    float acc[4][4] = {};
    for (int k0 = 0; k0 < 152; k0 += 8) {
        float2 av = *(const float2*)&A[(size_t)(m0 + a_m)*152 + k0 + a_k];
        float2 bv = make_float2(0.f, 0.f);
        if (n0 + a_m < 800)
            bv = *(const float2*)&Wc[(size_t)(n0 + a_m)*152 + k0 + a_k];
        __syncthreads();
        As[a_k][a_m] = av.x; As[a_k+1][a_m] = av.y;
        Bs[a_k][a_m] = bv.x; Bs[a_k+1][a_m] = bv.y;
        __syncthreads();
#pragma unroll
        for (int kk = 0; kk < 8; ++kk) {
            float4 a4 = *(const float4*)&As[kk][ty*4];
            float4 b4 = *(const float4*)&Bs[kk][tx*4];
            float am[4] = {a4.x, a4.y, a4.z, a4.w};
            float bn[4] = {b4.x, b4.y, b4.z, b4.w};
#pragma unroll
            for (int p = 0; p < 4; ++p)
#pragma unroll
                for (int q = 0; q < 4; ++q) acc[p][q] += am[p]*bn[q];
        }
    }
#pragma unroll
    for (int p = 0; p < 4; ++p) {
        int m = m0 + ty*4 + p;
#pragma unroll
        for (int q = 0; q < 4; ++q) {
            int n = n0 + tx*4 + q;
            if (n < 800) {
                int dir = n >= 400 ? 1 : 0, r = n - dir*400;
                int gg = r / 100, uu = r - gg*100;
                gates[((size_t)dir*TOK + m)*400 + uu*4 + gg]
                    = __float2bfloat16(acc[p][q] + bc[n]);
            }
        }
    }
}

// ---- K4: word BiLSTM. 256 blocks=(b,dir); 512 threads, 4-way k-split, f16x2
//      dot2 weights. v4: gates staged through double-buffered LDS in 16-step
//      chunks (coalesced b64 loads issued at chunk step 0, ds_write at step 15)
//      — v3 paid exposed HBM/L3 latency EVERY step because the implicit
//      vmcnt(0) before each s_barrier drained its per-step gate prefetch
//      (dur unchanged while VALUBusy halved 85->50: latency-bound proof).
__global__ __launch_bounds__(512)
__attribute__((amdgpu_waves_per_eu(2, 2)))
void k_word(
        const __hip_bfloat16* __restrict__ gates,
        const float* __restrict__ whh_f, const float* __restrict__ whh_b,
        __hip_bfloat16* __restrict__ wh) {
    int b = blockIdx.x >> 1, dir = blockIdx.x & 1;
    int tid = threadIdx.x;
    int wv   = tid >> 6;            // wave 0..7
    int lane = tid & 63;
    int kq   = lane >> 4;           // k-quarter: f16x2 dword chunks 4*i+kq
    int u    = wv*16 + (lane & 15); // unit 0..127
    bool act = (u < 100);
    const float* whh = dir ? whh_b : whh_f;
    __shared__ uint32_t Hs[2][64];                    // double-buffered f16x2 h
    __shared__ __align__(16) unsigned short GL[2][16*400];  // gate chunks, 25.6 KB
    for (int i = tid; i < 128; i += 512) ((uint32_t*)Hs)[i] = 0;
    // weights: W[gate][i] = f16x2 of Whh[gate*100+u][k=2d,2d+1], d=4i+kq (<50)
    f16x2 W[4][13];
#pragma unroll
    for (int gi = 0; gi < 4; ++gi)
#pragma unroll
        for (int i = 0; i < 13; ++i) {
            int d = 4*i + kq;
            f16x2 v = {};
            if (act && d < 50) {
                const float* r = &whh[(size_t)(gi*100 + u)*100 + 2*d];
                v.x = (f16)r[0]; v.y = (f16)r[1];
            }
            W[gi][i] = v;
        }
    const unsigned short* gp = (const unsigned short*)gates
                             + (size_t)(dir*TOK + b*256)*400;   // [t][u*4+gate]
    // prologue: stage chunk 0 (rows [tlo, tlo+16) are contiguous in memory)
    {
        int tlo = dir ? 240 : 0;
        const ushort4* src = (const ushort4*)(gp + (size_t)tlo*400);
        ushort4* dst = (ushort4*)GL[0];
#pragma unroll
        for (int i = 0; i < 4; ++i) {
            int idx = tid + 512*i;
            if (idx < 1600) dst[idx] = src[idx];
        }
    }
    float cst = 0.f;
    ushort4 R0 = {}, R1 = {}, R2 = {}, R3 = {};
    __syncthreads();
    for (int c = 0; c < 16; ++c) {
        int buf = c & 1;
#pragma unroll 1
        for (int ss = 0; ss < 16; ++ss) {
            int sidx = c*16 + ss;
            int t   = dir ? (255 - sidx) : sidx;
            int row = dir ? (15 - ss) : ss;
            // current-step gate quad: ds_read issued now, consumed after shuffles
            ushort4 Gq = *(const ushort4*)&GL[buf][row*400 + (act ? u*4 : 0)];
            // chunk c+1 global loads: 15 steps of flight before use
            if (ss == 0 && c < 15) {
                int tlo2 = dir ? (240 - 16*(c+1)) : (16*(c+1));
                const ushort4* src = (const ushort4*)(gp + (size_t)tlo2*400);
                R0 = src[tid]; R1 = src[tid+512]; R2 = src[tid+1024];
                if (tid < 64) R3 = src[tid+1536];
            }
            const uint32_t* hp = Hs[sidx & 1];
            float a0 = 0.f, a1 = 0.f, a2 = 0.f, a3 = 0.f;
#pragma unroll
            for (int i = 0; i < 13; ++i) {
                f16x2 h2 = u2h2(hp[4*i + kq]);  // same-addr broadcast per 16-lane group
                a0 = dot2(W[0][i], h2, a0);
                a1 = dot2(W[1][i], h2, a1);
                a2 = dot2(W[2][i], h2, a2);
                a3 = dot2(W[3][i], h2, a3);
            }
            // write staged regs to the other LDS buffer (visible after barrier)
            if (ss == 15 && c < 15) {
                ushort4* dst = (ushort4*)GL[buf ^ 1];
                dst[tid] = R0; dst[tid+512] = R1; dst[tid+1024] = R2;
                if (tid < 64) dst[tid+1536] = R3;
            }
            a0 += __shfl_xor(a0, 16, 64); a0 += __shfl_xor(a0, 32, 64);
            a1 += __shfl_xor(a1, 16, 64); a1 += __shfl_xor(a1, 32, 64);
            a2 += __shfl_xor(a2, 16, 64); a2 += __shfl_xor(a2, 32, 64);
            a3 += __shfl_xor(a3, 16, 64); a3 += __shfl_xor(a3, 32, 64);
            float gI = bf2f(Gq.x) + a0, gF = bf2f(Gq.y) + a1;
            float gG = bf2f(Gq.z) + a2, gO = bf2f(Gq.w) + a3;
            cst = sigf(gF)*cst + sigf(gI)*tanhfast(gG);
            float h = sigf(gO)*tanhfast(cst);
            if (act && kq == 0) {
                union { f16 hh; unsigned short us; } cv; cv.hh = (f16)h;
                ((unsigned short*)Hs[(sidx + 1) & 1])[u] = cv.us;
                wh[(size_t)(b*256 + t)*200 + dir*100 + u] = __float2bfloat16(h);
            }
            __syncthreads();
        }
    }
}

// ---- K5: feats = (tanh(wh@W1^T+b1)@W2^T+b2)*mask ; 32 tokens per block
__global__ __launch_bounds__(256) void k_feats(
        const __hip_bfloat16* __restrict__ wh,
        const float* __restrict__ W1, const float* __restrict__ b1,
        const float* __restrict__ W2, const float* __restrict__ b2,
        const int* __restrict__ word_num, float* __restrict__ feats) {
    __shared__ float As[8][32];
    __shared__ float Ws[8][100];
    __shared__ float mids[32][100];
    int tid = threadIdx.x;
    int m0  = blockIdx.x * 32;
    int a_m = tid >> 3, a_k = tid & 7;
    int tn  = tid % 25, tm = tid / 25;   // active: tid < 200
    float acc[4][4] = {};
    for (int k0 = 0; k0 < 200; k0 += 8) {
        float av = __bfloat162float(wh[(size_t)(m0 + a_m)*200 + k0 + a_k]);
        int i1 = tid + 256, i2 = tid + 512, i3 = tid + 768;
        float wv0 = W1[(tid>>3)*200 + k0 + (tid&7)];
        float wv1 = W1[(i1 >>3)*200 + k0 + (i1 &7)];
        float wv2 = W1[(i2 >>3)*200 + k0 + (i2 &7)];
        float wv3 = (i3 < 800) ? W1[(i3>>3)*200 + k0 + (i3&7)] : 0.f;
        __syncthreads();
        As[a_k][a_m] = av;
        Ws[tid&7][tid>>3] = wv0;
        Ws[i1 &7][i1 >>3] = wv1;
        Ws[i2 &7][i2 >>3] = wv2;
        if (i3 < 800) Ws[i3&7][i3>>3] = wv3;
        __syncthreads();
        if (tid < 200) {
#pragma unroll
            for (int kk = 0; kk < 8; ++kk) {
                float4 a4 = *(const float4*)&As[kk][tm*4];
                float4 w4 = *(const float4*)&Ws[kk][tn*4];
                float am[4] = {a4.x, a4.y, a4.z, a4.w};
                float wn[4] = {w4.x, w4.y, w4.z, w4.w};
#pragma unroll
                for (int p = 0; p < 4; ++p)
#pragma unroll
                    for (int q = 0; q < 4; ++q) acc[p][q] += am[p]*wn[q];
            }
        }
    }
    if (tid < 200) {
#pragma unroll
        for (int p = 0; p < 4; ++p)
#pragma unroll
            for (int q = 0; q < 4; ++q)
                mids[tm*4+p][tn*4+q] = tanhfast(acc[p][q] + b1[tn*4+q]);
    }
    __syncthreads();
    for (int idx = tid; idx < 288; idx += 256) {
        int tok = idx / 9, lab = idx - tok*9;
        int m = m0 + tok, bb = m >> 8, s = m & 255;
        float v = b2[lab];
        const float4* mp = (const float4*)mids[tok];
        const float4* wp = (const float4*)(W2 + lab*100);
#pragma unroll
        for (int k = 0; k < 25; ++k) {
            float4 mv = mp[k], wv = wp[k];
            v += mv.x*wv.x + mv.y*wv.y + mv.z*wv.z + mv.w*wv.w;
        }
        feats[(size_t)m*12 + lab] = (s < word_num[bb]) ? v : 0.f;
    }
}

// ---- K6: CRF numerator + log-forward recursion. One wave per batch row.
__global__ __launch_bounds__(64) void k_crf(
        const float* __restrict__ feats, const float* __restrict__ T,
        const int* __restrict__ word_num, const int* __restrict__ label_ids,
        float* __restrict__ perb) {
    int b = blockIdx.x, lane = threadIdx.x;
    int n = word_num[b];
    const int*   lab = label_ids + b*256;
    const float* fb  = feats + (size_t)b*256*12;
    float nm = 0.f;
    for (int t = lane; t < n; t += 64) {
        int lt = lab[t];
        int lp = (t == 0) ? 9 : lab[t-1];
        nm += fb[t*12 + lt] + T[lp*11 + lt];
    }
#pragma unroll
    for (int o = 32; o > 0; o >>= 1) nm += __shfl_down(nm, o, 64);
    nm = __shfl(nm, 0, 64);
    nm += T[lab[n-1]*11 + 10];
    int j = lane;
    float Tc[11];
#pragma unroll
    for (int i = 0; i < 11; ++i) Tc[i] = T[i*11 + (j < 11 ? j : 0)];
    float alpha = (j == 9) ? 0.f : -1000.f;
    for (int t = 0; t < n; ++t) {
        float obs = (j < 9) ? fb[t*12 + j] : -1000.f;
        float v[11], mx = -1e30f;
#pragma unroll
        for (int i = 0; i < 11; ++i) { v[i] = __shfl(alpha, i, 64) + Tc[i]; mx = fmaxf(mx, v[i]); }
        float ssum = 0.f;
#pragma unroll
        for (int i = 0; i < 11; ++i) ssum += __expf(v[i] - mx);
        alpha = obs + mx + __logf(ssum);
    }
    float vv[11], mx = -1e30f, ssum = 0.f;
#pragma unroll
    for (int i = 0; i < 11; ++i) { vv[i] = __shfl(alpha, i, 64) + Tc[i]; mx = fmaxf(mx, vv[i]); }
#pragma unroll
    for (int i = 0; i < 11; ++i) ssum += __expf(vv[i] - mx);
    float denom = __shfl(mx + __logf(ssum), 10, 64);
    if (lane == 0) perb[b] = denom - nm;
}

// ---- K7: mean over batch
__global__ void k_reduce(const float* __restrict__ perb, float* __restrict__ out) {
    int t = threadIdx.x;
    float v = perb[t];
#pragma unroll
    for (int o = 32; o > 0; o >>= 1) v += __shfl_down(v, o, 64);
    __shared__ float sm[2];
    if ((t & 63) == 0) sm[t >> 6] = v;
    __syncthreads();
    if (t == 0) out[0] = (sm[0] + sm[1]) * (1.0f/128.0f);
}

extern "C" void kernel_launch(void* const* d_in, const int* in_sizes, int n_in,
                              void* d_out, int out_size, void* d_ws, size_t ws_size,
                              hipStream_t stream) {
    const float* word_emb = (const float*)d_in[0];
    const float* char_emb = (const float*)d_in[1];
    const float* cWih_f   = (const float*)d_in[2];
    const float* cWhh_f   = (const float*)d_in[3];
    const float* cb_f     = (const float*)d_in[4];
    const float* cWih_b   = (const float*)d_in[5];
    const float* cWhh_b   = (const float*)d_in[6];
    const float* cb_b     = (const float*)d_in[7];
    const float* wWih_f   = (const float*)d_in[8];
    const float* wWhh_f   = (const float*)d_in[9];
    const float* wb_f     = (const float*)d_in[10];
    const float* wWih_b   = (const float*)d_in[11];
    const float* wWhh_b   = (const float*)d_in[12];
    const float* wb_b     = (const float*)d_in[13];
    const float* W1       = (const float*)d_in[14];
    const float* b1       = (const float*)d_in[15];
    const float* W2       = (const float*)d_in[16];
    const float* b2       = (const float*)d_in[17];
    const float* T        = (const float*)d_in[18];
    const int* word_num   = (const int*)d_in[19];
    const int* word_ids   = (const int*)d_in[20];
    const int* char_ids   = (const int*)d_in[21];
    const int* label_ids  = (const int*)d_in[22];

    char* ws = (char*)d_ws;
    float* gin            = (float*)(ws);                       //    80,000 B
    float* Wc             = (float*)(ws + 80000);               //   486,400 B
    float* bc             = (float*)(ws + 566400);              //     3,200 B
    float* wfbuf          = (float*)(ws + 569600);              // 19,922,944 B [32768][152]
    __hip_bfloat16* gates = (__hip_bfloat16*)(ws + 20492544);   // 52,428,800 B [2][32768][400]
    __hip_bfloat16* wh    = (__hip_bfloat16*)(ws + 72921344);   // 13,107,200 B [32768][200]
    float* feats          = (float*)(ws + 86028544);            //  1,572,864 B [32768][12]
    float* perb           = (float*)(ws + 87601408);            //       512 B
    // wpadh (10,400 B, f16) aliases head of `gates`: k_wpad -> k_char ->
    // overwritten by k_gemm_in (strictly serial on stream).
    unsigned short* wpadh = (unsigned short*)(ws + 20492544);

    k_gin   <<<4, 64, 0, stream>>>(char_emb, cWih_f, cb_f, cWih_b, cb_b, gin);
    k_wcomb <<<(800*152 + 255)/256, 256, 0, stream>>>(wWih_f, wb_f, wWih_b, wb_b, Wc, bc);
    k_wpad  <<<(2*4*25*26 + 255)/256, 256, 0, stream>>>(cWhh_f, cWhh_b, wpadh);
    k_gather<<<(TOK*152)/256, 256, 0, stream>>>(word_emb, word_ids, wfbuf);
    k_char  <<<8192, 256, 0, stream>>>(wpadh, gin, char_ids, word_num, wfbuf);
    k_gemm_in<<<512*13, 256, 0, stream>>>(wfbuf, Wc, bc, gates);
    k_word  <<<256, 512, 0, stream>>>(gates, wWhh_f, wWhh_b, wh);
    k_feats <<<1024, 256, 0, stream>>>(wh, W1, b1, W2, b2, word_num, feats);
    k_crf   <<<128, 64, 0, stream>>>(feats, T, word_num, label_ids, perb);
    k_reduce<<<1, 128, 0, stream>>>(perb, (float*)d_out);
}